// Round 1
// baseline (6031.819 us; speedup 1.0000x reference)
//
#include <hip/hip_runtime.h>
#include <hip/hip_bf16.h>
#include <math.h>

// GraphCast processor, fp32 baseline.
// Key restructuring: edge MLP's node-dependent terms hoisted to per-node GEMMs
//   P1 = x @ We_w[0:256], P2 = x @ We_w[256:512]   (E ~= 4N, so 4x FLOP savings)
//   h[e] = P1[dst[e]] + P2[src[e]] + attr[e] @ We_w[512:516] + We_b
// Layer pipeline (6x, sequential):
//   gemm P1, gemm P2 -> memset agg -> edge kernel (gather+LN+SiLU+atomic segsum)
//   -> gemm u=[x|agg]@Wn1+b -> LN+SiLU in place -> gemm x += v@Wn2 + b (in-place residual)

#define NNODES 40962
#define LFEAT 256
#define NEDGES 163848
#define NLAYERS 6

#define BM 64
#define BN 64
#define BK 16

// C[M x 256-col-slab] = A @ B (+bias) (+resid). A = concat_K(A1, A2) when A2 != null.
// A1/A2 are [M,256] row-major (ld=256). B is [K,256] row-major (ld=256).
// C has leading dim ldC. Launch grid: (ceil(M/64), 4), block 256.
__global__ __launch_bounds__(256) void gemm256(
    const float* __restrict__ A1, const float* __restrict__ A2,
    const float* __restrict__ B, const float* __restrict__ bias,
    const float* __restrict__ resid, float* __restrict__ C,
    int M, int K, int ldC)
{
    __shared__ float As[BK][BM];
    __shared__ float Bs[BK][BN];

    const int tid = threadIdx.x;
    const int m0 = blockIdx.x * BM;
    const int n0 = blockIdx.y * BN;
    const int tm = tid >> 4;          // 0..15
    const int tn = tid & 15;          // 0..15

    // A-tile load map: each thread loads float4: row = tid>>2 (0..63), k4 = (tid&3)*4
    const int arow = tid >> 2;
    const int ak   = (tid & 3) * 4;
    // B-tile load map: bk = tid>>4 (0..15), bn4 = (tid&15)*4
    const int bk  = tid >> 4;
    const int bn4 = (tid & 15) * 4;

    float acc[4][4] = {{0.f}};

    for (int k0 = 0; k0 < K; k0 += BK) {
        // pick A source half (K-concat of two ld-256 matrices)
        const float* Asrc;
        int kb;
        if (A2 == nullptr || k0 < 256) { Asrc = A1; kb = k0; }
        else                           { Asrc = A2; kb = k0 - 256; }

        const int gr = m0 + arow;
        float4 av = make_float4(0.f, 0.f, 0.f, 0.f);
        if (gr < M) av = *(const float4*)(Asrc + (size_t)gr * 256 + kb + ak);
        As[ak + 0][arow] = av.x;
        As[ak + 1][arow] = av.y;
        As[ak + 2][arow] = av.z;
        As[ak + 3][arow] = av.w;

        float4 bv = *(const float4*)(B + (size_t)(k0 + bk) * 256 + n0 + bn4);
        *(float4*)&Bs[bk][bn4] = bv;

        __syncthreads();

        #pragma unroll
        for (int k = 0; k < BK; ++k) {
            float a0 = As[k][tm * 4 + 0];
            float a1 = As[k][tm * 4 + 1];
            float a2 = As[k][tm * 4 + 2];
            float a3 = As[k][tm * 4 + 3];
            float b0 = Bs[k][tn * 4 + 0];
            float b1 = Bs[k][tn * 4 + 1];
            float b2 = Bs[k][tn * 4 + 2];
            float b3 = Bs[k][tn * 4 + 3];
            acc[0][0] += a0 * b0; acc[0][1] += a0 * b1; acc[0][2] += a0 * b2; acc[0][3] += a0 * b3;
            acc[1][0] += a1 * b0; acc[1][1] += a1 * b1; acc[1][2] += a1 * b2; acc[1][3] += a1 * b3;
            acc[2][0] += a2 * b0; acc[2][1] += a2 * b1; acc[2][2] += a2 * b2; acc[2][3] += a2 * b3;
            acc[3][0] += a3 * b0; acc[3][1] += a3 * b1; acc[3][2] += a3 * b2; acc[3][3] += a3 * b3;
        }
        __syncthreads();
    }

    #pragma unroll
    for (int i = 0; i < 4; ++i) {
        const int gr = m0 + tm * 4 + i;
        if (gr >= M) continue;
        #pragma unroll
        for (int j = 0; j < 4; ++j) {
            const int col = n0 + tn * 4 + j;
            float v = acc[i][j];
            if (bias)  v += bias[col];
            if (resid) v += resid[(size_t)gr * ldC + col];
            C[(size_t)gr * ldC + col] = v;
        }
    }
}

__device__ __forceinline__ float wave_sum(float v) {
    #pragma unroll
    for (int o = 32; o > 0; o >>= 1) v += __shfl_xor(v, o);
    return v;
}

// One wave (64 lanes) per edge; 4 cols/lane.
// h = P1[dst] + P2[src] + attr@W3 + be; msg = silu(LN(h,g1,b1)); agg[dst] += msg.
__global__ __launch_bounds__(256) void edge_kernel(
    const float* __restrict__ P,      // [N,512]: cols 0..255 = x@W1, 256..511 = x@W2
    const int* __restrict__ src, const int* __restrict__ dst,
    const float* __restrict__ attr,   // [E,4]
    const float* __restrict__ W3,     // [4,256]
    const float* __restrict__ be, const float* __restrict__ g1, const float* __restrict__ b1,
    float* __restrict__ agg, int E)
{
    const int wave = threadIdx.x >> 6;
    const int lane = threadIdx.x & 63;
    const int e = blockIdx.x * 4 + wave;
    if (e >= E) return;

    const int s = src[e];
    const int d = dst[e];
    const int c0 = lane * 4;

    float4 pd = *(const float4*)(P + (size_t)d * 512 + c0);
    float4 ps = *(const float4*)(P + (size_t)s * 512 + 256 + c0);
    const float a0 = attr[e * 4 + 0];
    const float a1 = attr[e * 4 + 1];
    const float a2 = attr[e * 4 + 2];
    const float a3 = attr[e * 4 + 3];

    float h[4];
    const float* pdp = (const float*)&pd;
    const float* psp = (const float*)&ps;
    #pragma unroll
    for (int i = 0; i < 4; ++i) {
        const int c = c0 + i;
        float w = a0 * W3[c] + a1 * W3[256 + c] + a2 * W3[512 + c] + a3 * W3[768 + c];
        h[i] = pdp[i] + psp[i] + w + be[c];
    }

    float sum = wave_sum(h[0] + h[1] + h[2] + h[3]);
    const float mean = sum * (1.0f / 256.0f);
    float vs = 0.f;
    #pragma unroll
    for (int i = 0; i < 4; ++i) { float t = h[i] - mean; vs += t * t; }
    vs = wave_sum(vs);
    const float rstd = rsqrtf(vs * (1.0f / 256.0f) + 1e-5f);

    #pragma unroll
    for (int i = 0; i < 4; ++i) {
        const int c = c0 + i;
        float y = (h[i] - mean) * rstd * g1[c] + b1[c];
        float m = y / (1.0f + __expf(-y));   // silu
        atomicAdd(agg + (size_t)d * 256 + c, m);
    }
}

// In-place LayerNorm + SiLU over rows of u [N,256]; one wave per row.
__global__ __launch_bounds__(256) void ln_silu_kernel(
    float* __restrict__ u, const float* __restrict__ g, const float* __restrict__ b, int N)
{
    const int wave = threadIdx.x >> 6;
    const int lane = threadIdx.x & 63;
    const int r = blockIdx.x * 4 + wave;
    if (r >= N) return;

    float4 hv = *(const float4*)(u + (size_t)r * 256 + lane * 4);
    float h[4] = {hv.x, hv.y, hv.z, hv.w};

    float sum = wave_sum(h[0] + h[1] + h[2] + h[3]);
    const float mean = sum * (1.0f / 256.0f);
    float vs = 0.f;
    #pragma unroll
    for (int i = 0; i < 4; ++i) { float t = h[i] - mean; vs += t * t; }
    vs = wave_sum(vs);
    const float rstd = rsqrtf(vs * (1.0f / 256.0f) + 1e-5f);

    #pragma unroll
    for (int i = 0; i < 4; ++i) {
        const int c = lane * 4 + i;
        float y = (h[i] - mean) * rstd * g[c] + b[c];
        h[i] = y / (1.0f + __expf(-y));
    }
    *(float4*)(u + (size_t)r * 256 + lane * 4) = make_float4(h[0], h[1], h[2], h[3]);
}

extern "C" void kernel_launch(void* const* d_in, const int* in_sizes, int n_in,
                              void* d_out, int out_size, void* d_ws, size_t ws_size,
                              hipStream_t stream) {
    const float* mesh   = (const float*)d_in[0];
    const int*   eidx   = (const int*)  d_in[1];
    const float* eattr  = (const float*)d_in[2];
    const float* We_w   = (const float*)d_in[3];
    const float* We_b   = (const float*)d_in[4];
    const float* ln1_g  = (const float*)d_in[5];
    const float* ln1_b  = (const float*)d_in[6];
    const float* Wn1_w  = (const float*)d_in[7];
    const float* Wn1_b  = (const float*)d_in[8];
    const float* ln2_g  = (const float*)d_in[9];
    const float* ln2_b  = (const float*)d_in[10];
    const float* Wn2_w  = (const float*)d_in[11];
    const float* Wn2_b  = (const float*)d_in[12];

    const int N = NNODES, E = NEDGES;

    float* x   = (float*)d_out;                 // [N,256] current latents
    float* P   = (float*)d_ws;                  // [N,512]
    float* agg = P + (size_t)N * 512;           // [N,256]
    float* u   = agg + (size_t)N * 256;         // [N,256]

    const int* src = eidx;          // edge_index[0]
    const int* dst = eidx + E;      // edge_index[1]

    // x <- mesh_latent
    hipMemcpyAsync(x, mesh, (size_t)N * 256 * sizeof(float),
                   hipMemcpyDeviceToDevice, stream);

    const dim3 gemm_grid((N + BM - 1) / BM, 4);
    const int edge_blocks = (E + 3) / 4;
    const int ln_blocks = (N + 3) / 4;

    for (int l = 0; l < NLAYERS; ++l) {
        const float* W1  = We_w + (size_t)l * 516 * 256;          // rows 0..255
        const float* W2  = W1 + (size_t)256 * 256;                // rows 256..511
        const float* W3  = W1 + (size_t)512 * 256;                // rows 512..515
        const float* be  = We_b  + (size_t)l * 256;
        const float* g1  = ln1_g + (size_t)l * 256;
        const float* b1  = ln1_b + (size_t)l * 256;
        const float* Wn1 = Wn1_w + (size_t)l * 512 * 256;
        const float* bn1 = Wn1_b + (size_t)l * 256;
        const float* g2  = ln2_g + (size_t)l * 256;
        const float* b2  = ln2_b + (size_t)l * 256;
        const float* Wn2 = Wn2_w + (size_t)l * 256 * 256;
        const float* bn2 = Wn2_b + (size_t)l * 256;

        // P1 = x @ W1  -> P[:, 0:256]
        gemm256<<<gemm_grid, 256, 0, stream>>>(x, nullptr, W1, nullptr, nullptr,
                                               P, N, 256, 512);
        // P2 = x @ W2  -> P[:, 256:512]
        gemm256<<<gemm_grid, 256, 0, stream>>>(x, nullptr, W2, nullptr, nullptr,
                                               P + 256, N, 256, 512);
        // agg = 0
        hipMemsetAsync(agg, 0, (size_t)N * 256 * sizeof(float), stream);
        // edge message + LN + SiLU + segment-sum
        edge_kernel<<<edge_blocks, 256, 0, stream>>>(P, src, dst, eattr, W3,
                                                     be, g1, b1, agg, E);
        // u = [x | agg] @ Wn1 + bn1
        gemm256<<<gemm_grid, 256, 0, stream>>>(x, agg, Wn1, bn1, nullptr,
                                               u, N, 512, 256);
        // u = silu(LN(u)) in place
        ln_silu_kernel<<<ln_blocks, 256, 0, stream>>>(u, g2, b2, N);
        // x = x + u @ Wn2 + bn2
        gemm256<<<gemm_grid, 256, 0, stream>>>(u, nullptr, Wn2, bn2, x,
                                               x, N, 256, 256);
    }
}

// Round 2
// 3189.666 us; speedup vs baseline: 1.8911x; 1.8911x over previous
//
#include <hip/hip_runtime.h>
#include <hip/hip_bf16.h>
#include <math.h>

// GraphCast processor, fp32, round 1.
// R1 change: eliminate device-scope fp32 atomics in aggregation (655 MB HBM RMW
// traffic per layer, 55% of runtime). Counting-sort edges by dst ONCE per launch
// -> CSR; fused per-node kernel walks incident edges, computes msg (gather P2[src],
// LN, SiLU) and register-accumulates agg. No [E,256] materialization, no atomics.
// u aliases P (P dead after aggregation) so ws footprint shrinks.

#define NNODES 40962
#define LFEAT 256
#define NEDGES 163848
#define NLAYERS 6

#define BM 64
#define BN 64
#define BK 16

// C[M x 64-col tile] = A @ B (+bias) (+resid). A = concat_K(A1, A2) when A2 != null.
// A1/A2 are [M,256] row-major (ld=256). B is [K,256] row-major.
__global__ __launch_bounds__(256) void gemm256(
    const float* __restrict__ A1, const float* __restrict__ A2,
    const float* __restrict__ B, const float* __restrict__ bias,
    const float* __restrict__ resid, float* __restrict__ C,
    int M, int K, int ldC)
{
    __shared__ float As[BK][BM];
    __shared__ float Bs[BK][BN];

    const int tid = threadIdx.x;
    const int m0 = blockIdx.x * BM;
    const int n0 = blockIdx.y * BN;
    const int tm = tid >> 4;          // 0..15
    const int tn = tid & 15;          // 0..15

    const int arow = tid >> 2;
    const int ak   = (tid & 3) * 4;
    const int bk  = tid >> 4;
    const int bn4 = (tid & 15) * 4;

    float acc[4][4] = {{0.f}};

    for (int k0 = 0; k0 < K; k0 += BK) {
        const float* Asrc;
        int kb;
        if (A2 == nullptr || k0 < 256) { Asrc = A1; kb = k0; }
        else                           { Asrc = A2; kb = k0 - 256; }

        const int gr = m0 + arow;
        float4 av = make_float4(0.f, 0.f, 0.f, 0.f);
        if (gr < M) av = *(const float4*)(Asrc + (size_t)gr * 256 + kb + ak);
        As[ak + 0][arow] = av.x;
        As[ak + 1][arow] = av.y;
        As[ak + 2][arow] = av.z;
        As[ak + 3][arow] = av.w;

        float4 bv = *(const float4*)(B + (size_t)(k0 + bk) * 256 + n0 + bn4);
        *(float4*)&Bs[bk][bn4] = bv;

        __syncthreads();

        #pragma unroll
        for (int k = 0; k < BK; ++k) {
            float a0 = As[k][tm * 4 + 0];
            float a1 = As[k][tm * 4 + 1];
            float a2 = As[k][tm * 4 + 2];
            float a3 = As[k][tm * 4 + 3];
            float b0 = Bs[k][tn * 4 + 0];
            float b1 = Bs[k][tn * 4 + 1];
            float b2 = Bs[k][tn * 4 + 2];
            float b3 = Bs[k][tn * 4 + 3];
            acc[0][0] += a0 * b0; acc[0][1] += a0 * b1; acc[0][2] += a0 * b2; acc[0][3] += a0 * b3;
            acc[1][0] += a1 * b0; acc[1][1] += a1 * b1; acc[1][2] += a1 * b2; acc[1][3] += a1 * b3;
            acc[2][0] += a2 * b0; acc[2][1] += a2 * b1; acc[2][2] += a2 * b2; acc[2][3] += a2 * b3;
            acc[3][0] += a3 * b0; acc[3][1] += a3 * b1; acc[3][2] += a3 * b2; acc[3][3] += a3 * b3;
        }
        __syncthreads();
    }

    #pragma unroll
    for (int i = 0; i < 4; ++i) {
        const int gr = m0 + tm * 4 + i;
        if (gr >= M) continue;
        #pragma unroll
        for (int j = 0; j < 4; ++j) {
            const int col = n0 + tn * 4 + j;
            float v = acc[i][j];
            if (bias)  v += bias[col];
            if (resid) v += resid[(size_t)gr * ldC + col];
            C[(size_t)gr * ldC + col] = v;
        }
    }
}

__device__ __forceinline__ float wave_sum(float v) {
    #pragma unroll
    for (int o = 32; o > 0; o >>= 1) v += __shfl_xor(v, o);
    return v;
}

// ---------------- CSR build (once per launch) ----------------

__global__ __launch_bounds__(256) void count_kernel(
    const int* __restrict__ dst, int* __restrict__ deg, int E)
{
    int e = blockIdx.x * 256 + threadIdx.x;
    if (e < E) atomicAdd(&deg[dst[e]], 1);
}

// Single-block exclusive scan over deg[0..n) -> rowptr[0..n], rowptr[n]=total.
__global__ __launch_bounds__(1024) void scan_kernel(
    const int* __restrict__ deg, int* __restrict__ rowptr, int n)
{
    __shared__ int wsum[16];
    __shared__ int carry_s;
    const int tid = threadIdx.x;
    const int lane = tid & 63, wave = tid >> 6;
    if (tid == 0) carry_s = 0;
    __syncthreads();

    for (int base = 0; base < n; base += 1024) {
        int i = base + tid;
        int v = (i < n) ? deg[i] : 0;
        int x = v;  // inclusive scan within wave
        #pragma unroll
        for (int o = 1; o < 64; o <<= 1) {
            int t = __shfl_up(x, o);
            if (lane >= o) x += t;
        }
        if (lane == 63) wsum[wave] = x;
        __syncthreads();
        if (wave == 0 && lane < 16) {
            int w = wsum[lane];
            #pragma unroll
            for (int o = 1; o < 16; o <<= 1) {
                int t = __shfl_up(w, o);
                if (lane >= o) w += t;
            }
            wsum[lane] = w;  // inclusive wave-sums
        }
        __syncthreads();
        int wave_off = (wave == 0) ? 0 : wsum[wave - 1];
        int incl = x + wave_off + carry_s;
        if (i < n) rowptr[i] = incl - v;   // exclusive
        __syncthreads();
        if (tid == 0) carry_s += wsum[15];
        __syncthreads();
    }
    if (tid == 0) rowptr[n] = carry_s;
}

__global__ __launch_bounds__(256) void scatter_kernel(
    const int* __restrict__ dst, int* __restrict__ cursor,
    int* __restrict__ esorted, int E)
{
    int e = blockIdx.x * 256 + threadIdx.x;
    if (e < E) {
        int p = atomicAdd(&cursor[dst[e]], 1);
        esorted[p] = e;
    }
}

// ---------------- fused per-node message + aggregate ----------------
// One wave per node, 4 cols/lane. For each incident edge (CSR by dst):
//   h = P1[n] + P2[src[e]] + attr[e]@W3 + be ; acc += silu(LN(h,g1,b1))
// agg[n] written once, streaming, no atomics.
__global__ __launch_bounds__(256) void node_agg_kernel(
    const float* __restrict__ P,      // [N,512]
    const int* __restrict__ src,
    const float* __restrict__ attr,   // [E,4]
    const float* __restrict__ W3,     // [4,256]
    const float* __restrict__ be, const float* __restrict__ g1, const float* __restrict__ b1,
    const int* __restrict__ rowptr, const int* __restrict__ esorted,
    float* __restrict__ agg, int N)
{
    const int wave = threadIdx.x >> 6;
    const int lane = threadIdx.x & 63;
    const int n = blockIdx.x * 4 + wave;
    if (n >= N) return;
    const int c0 = lane * 4;

    float4 p1 = *(const float4*)(P + (size_t)n * 512 + c0);
    const float* p1p = (const float*)&p1;

    // per-lane column constants
    float w30[4], w31[4], w32[4], w33[4], bev[4], g1v[4], b1v[4];
    #pragma unroll
    for (int i = 0; i < 4; ++i) {
        const int c = c0 + i;
        w30[i] = W3[c]; w31[i] = W3[256 + c]; w32[i] = W3[512 + c]; w33[i] = W3[768 + c];
        bev[i] = be[c]; g1v[i] = g1[c]; b1v[i] = b1[c];
    }

    float acc[4] = {0.f, 0.f, 0.f, 0.f};
    const int beg = rowptr[n];
    const int end = rowptr[n + 1];

    for (int i = beg; i < end; ++i) {
        const int e = esorted[i];
        const int s = src[e];
        float4 ps = *(const float4*)(P + (size_t)s * 512 + 256 + c0);
        const float* psp = (const float*)&ps;
        float4 av = *(const float4*)(attr + (size_t)e * 4);

        float h[4];
        #pragma unroll
        for (int j = 0; j < 4; ++j) {
            float w = av.x * w30[j] + av.y * w31[j] + av.z * w32[j] + av.w * w33[j];
            h[j] = p1p[j] + psp[j] + w + bev[j];
        }

        float sum = wave_sum(h[0] + h[1] + h[2] + h[3]);
        const float mean = sum * (1.0f / 256.0f);
        float vs = 0.f;
        #pragma unroll
        for (int j = 0; j < 4; ++j) { float t = h[j] - mean; vs += t * t; }
        vs = wave_sum(vs);
        const float rstd = rsqrtf(vs * (1.0f / 256.0f) + 1e-5f);

        #pragma unroll
        for (int j = 0; j < 4; ++j) {
            float y = (h[j] - mean) * rstd * g1v[j] + b1v[j];
            acc[j] += y / (1.0f + __expf(-y));
        }
    }

    *(float4*)(agg + (size_t)n * 256 + c0) = make_float4(acc[0], acc[1], acc[2], acc[3]);
}

// In-place LayerNorm + SiLU over rows of u [N,256]; one wave per row.
__global__ __launch_bounds__(256) void ln_silu_kernel(
    float* __restrict__ u, const float* __restrict__ g, const float* __restrict__ b, int N)
{
    const int wave = threadIdx.x >> 6;
    const int lane = threadIdx.x & 63;
    const int r = blockIdx.x * 4 + wave;
    if (r >= N) return;

    float4 hv = *(const float4*)(u + (size_t)r * 256 + lane * 4);
    float h[4] = {hv.x, hv.y, hv.z, hv.w};

    float sum = wave_sum(h[0] + h[1] + h[2] + h[3]);
    const float mean = sum * (1.0f / 256.0f);
    float vs = 0.f;
    #pragma unroll
    for (int i = 0; i < 4; ++i) { float t = h[i] - mean; vs += t * t; }
    vs = wave_sum(vs);
    const float rstd = rsqrtf(vs * (1.0f / 256.0f) + 1e-5f);

    #pragma unroll
    for (int i = 0; i < 4; ++i) {
        const int c = lane * 4 + i;
        float y = (h[i] - mean) * rstd * g[c] + b[c];
        h[i] = y / (1.0f + __expf(-y));
    }
    *(float4*)(u + (size_t)r * 256 + lane * 4) = make_float4(h[0], h[1], h[2], h[3]);
}

extern "C" void kernel_launch(void* const* d_in, const int* in_sizes, int n_in,
                              void* d_out, int out_size, void* d_ws, size_t ws_size,
                              hipStream_t stream) {
    const float* mesh   = (const float*)d_in[0];
    const int*   eidx   = (const int*)  d_in[1];
    const float* eattr  = (const float*)d_in[2];
    const float* We_w   = (const float*)d_in[3];
    const float* We_b   = (const float*)d_in[4];
    const float* ln1_g  = (const float*)d_in[5];
    const float* ln1_b  = (const float*)d_in[6];
    const float* Wn1_w  = (const float*)d_in[7];
    const float* Wn1_b  = (const float*)d_in[8];
    const float* ln2_g  = (const float*)d_in[9];
    const float* ln2_b  = (const float*)d_in[10];
    const float* Wn2_w  = (const float*)d_in[11];
    const float* Wn2_b  = (const float*)d_in[12];

    const int N = NNODES, E = NEDGES;

    float* x   = (float*)d_out;                 // [N,256] current latents
    float* P   = (float*)d_ws;                  // [N,512]
    float* u   = P;                             // [N,256] aliases P (P dead by then)
    float* agg = P + (size_t)N * 512;           // [N,256]
    int*   deg     = (int*)(agg + (size_t)N * 256);
    int*   rowptr  = deg + N;                   // N+1
    int*   cursor  = rowptr + (N + 1);
    int*   esorted = cursor + N;                // E

    const int* src = eidx;          // edge_index[0]
    const int* dst = eidx + E;      // edge_index[1]

    // x <- mesh_latent
    hipMemcpyAsync(x, mesh, (size_t)N * 256 * sizeof(float),
                   hipMemcpyDeviceToDevice, stream);

    // ---- CSR build (once) ----
    hipMemsetAsync(deg, 0, (size_t)N * sizeof(int), stream);
    count_kernel<<<(E + 255) / 256, 256, 0, stream>>>(dst, deg, E);
    scan_kernel<<<1, 1024, 0, stream>>>(deg, rowptr, N);
    hipMemcpyAsync(cursor, rowptr, (size_t)N * sizeof(int),
                   hipMemcpyDeviceToDevice, stream);
    scatter_kernel<<<(E + 255) / 256, 256, 0, stream>>>(dst, cursor, esorted, E);

    const dim3 gemm_grid((N + BM - 1) / BM, 4);
    const int node_blocks = (N + 3) / 4;

    for (int l = 0; l < NLAYERS; ++l) {
        const float* W1  = We_w + (size_t)l * 516 * 256;
        const float* W2  = W1 + (size_t)256 * 256;
        const float* W3  = W1 + (size_t)512 * 256;
        const float* be  = We_b  + (size_t)l * 256;
        const float* g1  = ln1_g + (size_t)l * 256;
        const float* b1  = ln1_b + (size_t)l * 256;
        const float* Wn1 = Wn1_w + (size_t)l * 512 * 256;
        const float* bn1 = Wn1_b + (size_t)l * 256;
        const float* g2  = ln2_g + (size_t)l * 256;
        const float* b2  = ln2_b + (size_t)l * 256;
        const float* Wn2 = Wn2_w + (size_t)l * 256 * 256;
        const float* bn2 = Wn2_b + (size_t)l * 256;

        // P1 = x @ W1 -> P[:,0:256];  P2 = x @ W2 -> P[:,256:512]
        gemm256<<<gemm_grid, 256, 0, stream>>>(x, nullptr, W1, nullptr, nullptr,
                                               P, N, 256, 512);
        gemm256<<<gemm_grid, 256, 0, stream>>>(x, nullptr, W2, nullptr, nullptr,
                                               P + 256, N, 256, 512);
        // fused edge-message + segment-sum (atomic-free)
        node_agg_kernel<<<node_blocks, 256, 0, stream>>>(P, src, eattr, W3,
                                                         be, g1, b1,
                                                         rowptr, esorted, agg, N);
        // u = [x | agg] @ Wn1 + bn1   (u aliases P; P dead)
        gemm256<<<gemm_grid, 256, 0, stream>>>(x, agg, Wn1, bn1, nullptr,
                                               u, N, 512, 256);
        // u = silu(LN(u)) in place
        ln_silu_kernel<<<node_blocks, 256, 0, stream>>>(u, g2, b2, N);
        // x = x + u @ Wn2 + bn2
        gemm256<<<gemm_grid, 256, 0, stream>>>(u, nullptr, Wn2, bn2, x,
                                               x, N, 256, 256);
    }
}

// Round 3
// 1526.800 us; speedup vs baseline: 3.9506x; 2.0891x over previous
//
#include <hip/hip_runtime.h>
#include <hip/hip_bf16.h>
#include <math.h>

// GraphCast processor, round 2: MFMA GEMMs.
// - Weights pre-transposed + RNE-rounded to bf16 [N][K] once per launch.
// - A (x / agg / u) split on the fly into bf16 hi+lo (A = hi+lo ~ fp32 precision);
//   each tile-pair does 2 MFMAs (hi*b, lo*b). B rounding (~2^-9 rel) dominates error.
// - GEMM: 128x128 tile, BK=32, 4 waves x (4x4) mfma_f32_16x16x32_bf16.
//   B staged via global_load_lds (16B/lane); A staged via ds_write_b128 with
//   +16B padded row stride (2-way LDS aliasing = free).
// - P1/P2 fused into one N=512 GEMM. CSR aggregation unchanged from R1.

#define NNODES 40962
#define NEDGES 163848
#define NLAYERS 6

typedef __attribute__((ext_vector_type(8))) short short8;
typedef __attribute__((ext_vector_type(4))) float f32x4;

__device__ __forceinline__ void async_copy16(void* lds, const void* g) {
    __builtin_amdgcn_global_load_lds(
        (const __attribute__((address_space(1))) unsigned int*)g,
        (__attribute__((address_space(3))) unsigned int*)lds, 16, 0, 0);
}

// ---------------- weight prep: transpose fp32 [R][C] -> bf16(RNE) [C][R] ----------------
// batch b: src += (b/halves)*src_lstride + (b%halves)*src_hstride; dst += b*R*C
__global__ __launch_bounds__(256) void wprep_kernel(
    const float* __restrict__ src, unsigned short* __restrict__ dst,
    int R, int C, size_t src_lstride, size_t src_hstride, int halves)
{
    __shared__ float t[32][33];
    const int b = blockIdx.z;
    src += (size_t)(b / halves) * src_lstride + (size_t)(b % halves) * src_hstride;
    dst += (size_t)b * R * C;
    const int tx = threadIdx.x & 31, ty = threadIdx.x >> 5;
    const int c0 = blockIdx.x * 32, r0 = blockIdx.y * 32;
    #pragma unroll
    for (int i = 0; i < 4; ++i)
        t[ty + 8 * i][tx] = src[(size_t)(r0 + ty + 8 * i) * C + c0 + tx];
    __syncthreads();
    #pragma unroll
    for (int i = 0; i < 4; ++i) {
        unsigned int u = __float_as_uint(t[tx][ty + 8 * i]);
        unsigned short h = (unsigned short)((u + 0x7FFFu + ((u >> 16) & 1u)) >> 16); // RNE
        dst[(size_t)(c0 + ty + 8 * i) * R + r0 + tx] = h;
    }
}

// ---------------- MFMA GEMM ----------------
// C[M x (grid.y*128 cols)] = (A1 K-concat A2) @ B (+bias) (+resid)
// A1/A2 fp32 row-major ld=256 (concat boundary at k=256). BT bf16 [N][K].
__global__ __launch_bounds__(256) void gemm_mfma(
    const float* __restrict__ A1, const float* __restrict__ A2,
    const unsigned short* __restrict__ BT,
    const float* __restrict__ bias, const float* __restrict__ resid,
    float* __restrict__ C, int M, int K, int ldC)
{
    // A rows padded: 32 shorts data + 8 pad = 40 shorts (80 B) stride
    __shared__ __align__(16) short Ah[128 * 40];
    __shared__ __align__(16) short Al[128 * 40];
    __shared__ __align__(16) short Bs[128 * 32];

    const int tid = threadIdx.x;
    const int wave = tid >> 6;
    const int lane = tid & 63;
    const int m0 = blockIdx.x * 128;
    const int n0 = blockIdx.y * 128;
    const int wm = wave >> 1;        // 0..1
    const int wn = wave & 1;         // 0..1
    const int fm = lane & 15;
    const int quad = lane >> 4;      // 0..3
    const int ko = quad * 8;

    // A staging map: thread -> row=tid>>1 (0..127), kh=(tid&1)*16
    const int arow = tid >> 1;
    const int akh = (tid & 1) * 16;
    const int gr_stage = m0 + arow;

    f32x4 acc[4][4];
    #pragma unroll
    for (int i = 0; i < 4; ++i)
        #pragma unroll
        for (int j = 0; j < 4; ++j)
            acc[i][j] = (f32x4){0.f, 0.f, 0.f, 0.f};

    const int nkt = K >> 5;
    for (int kt = 0; kt < nkt; ++kt) {
        const int k0 = kt << 5;
        const float* Asrc; int kb;
        if (A2 != nullptr && k0 >= 256) { Asrc = A2; kb = k0 - 256; }
        else                            { Asrc = A1; kb = k0; }

        // --- B: async global->LDS, 2 chunks of 1KB per wave ---
        {
            const int n_row = wave * 32 + (lane >> 2);
            const char* gbase = (const char*)BT + (((size_t)(n0 + n_row) * K + k0) << 1)
                              + ((lane & 3) << 4);
            char* lbase = (char*)Bs + wave * 2048;
            async_copy16(lbase, gbase);
            const char* gbase2 = gbase + ((size_t)16 * K << 1); // +16 rows
            async_copy16(lbase + 1024, gbase2);
        }

        // --- A: fp32 load -> hi/lo bf16 split -> LDS ---
        {
            float f[16];
            if (gr_stage < M) {
                const float* ap = Asrc + (size_t)gr_stage * 256 + kb + akh;
                #pragma unroll
                for (int i = 0; i < 4; ++i) {
                    f32x4 v = *(const f32x4*)(ap + 4 * i);
                    f[4 * i + 0] = v.x; f[4 * i + 1] = v.y;
                    f[4 * i + 2] = v.z; f[4 * i + 3] = v.w;
                }
            } else {
                #pragma unroll
                for (int i = 0; i < 16; ++i) f[i] = 0.f;
            }
            unsigned int hid[8], lod[8];
            #pragma unroll
            for (int i = 0; i < 8; ++i) {
                unsigned int u0 = __float_as_uint(f[2 * i]);
                unsigned int u1 = __float_as_uint(f[2 * i + 1]);
                float l0 = f[2 * i]     - __uint_as_float(u0 & 0xFFFF0000u);
                float l1 = f[2 * i + 1] - __uint_as_float(u1 & 0xFFFF0000u);
                hid[i] = (u0 >> 16) | (u1 & 0xFFFF0000u);
                lod[i] = (__float_as_uint(l0) >> 16) | (__float_as_uint(l1) & 0xFFFF0000u);
            }
            short* ah = &Ah[arow * 40 + akh];
            short* al = &Al[arow * 40 + akh];
            ((uint4*)ah)[0] = make_uint4(hid[0], hid[1], hid[2], hid[3]);
            ((uint4*)ah)[1] = make_uint4(hid[4], hid[5], hid[6], hid[7]);
            ((uint4*)al)[0] = make_uint4(lod[0], lod[1], lod[2], lod[3]);
            ((uint4*)al)[1] = make_uint4(lod[4], lod[5], lod[6], lod[7]);
        }

        __syncthreads();

        // --- fragments + MFMA ---
        short8 afh[4], afl[4], bf[4];
        #pragma unroll
        for (int i = 0; i < 4; ++i) {
            const int r = wm * 64 + i * 16 + fm;
            afh[i] = *(const short8*)&Ah[r * 40 + ko];
            afl[i] = *(const short8*)&Al[r * 40 + ko];
        }
        #pragma unroll
        for (int j = 0; j < 4; ++j) {
            const int r = wn * 64 + j * 16 + fm;
            bf[j] = *(const short8*)&Bs[r * 32 + ko];
        }
        #pragma unroll
        for (int i = 0; i < 4; ++i)
            #pragma unroll
            for (int j = 0; j < 4; ++j) {
                acc[i][j] = __builtin_amdgcn_mfma_f32_16x16x32_bf16(afl[i], bf[j], acc[i][j], 0, 0, 0);
                acc[i][j] = __builtin_amdgcn_mfma_f32_16x16x32_bf16(afh[i], bf[j], acc[i][j], 0, 0, 0);
            }

        __syncthreads();
    }

    // --- epilogue: C/D layout col=lane&15, row=quad*4+reg ---
    #pragma unroll
    for (int j = 0; j < 4; ++j) {
        const int gc = n0 + wn * 64 + j * 16 + fm;
        const float bj = bias ? bias[gc] : 0.f;
        #pragma unroll
        for (int i = 0; i < 4; ++i) {
            #pragma unroll
            for (int r = 0; r < 4; ++r) {
                const int gr = m0 + wm * 64 + i * 16 + quad * 4 + r;
                if (gr < M) {
                    float v = acc[i][j][r] + bj;
                    if (resid) v += resid[(size_t)gr * ldC + gc];
                    C[(size_t)gr * ldC + gc] = v;
                }
            }
        }
    }
}

__device__ __forceinline__ float wave_sum(float v) {
    #pragma unroll
    for (int o = 32; o > 0; o >>= 1) v += __shfl_xor(v, o);
    return v;
}

// ---------------- CSR build (once per launch) ----------------
__global__ __launch_bounds__(256) void count_kernel(
    const int* __restrict__ dst, int* __restrict__ deg, int E)
{
    int e = blockIdx.x * 256 + threadIdx.x;
    if (e < E) atomicAdd(&deg[dst[e]], 1);
}

__global__ __launch_bounds__(1024) void scan_kernel(
    const int* __restrict__ deg, int* __restrict__ rowptr, int n)
{
    __shared__ int wsum[16];
    __shared__ int carry_s;
    const int tid = threadIdx.x;
    const int lane = tid & 63, wave = tid >> 6;
    if (tid == 0) carry_s = 0;
    __syncthreads();

    for (int base = 0; base < n; base += 1024) {
        int i = base + tid;
        int v = (i < n) ? deg[i] : 0;
        int x = v;
        #pragma unroll
        for (int o = 1; o < 64; o <<= 1) {
            int t = __shfl_up(x, o);
            if (lane >= o) x += t;
        }
        if (lane == 63) wsum[wave] = x;
        __syncthreads();
        if (wave == 0 && lane < 16) {
            int w = wsum[lane];
            #pragma unroll
            for (int o = 1; o < 16; o <<= 1) {
                int t = __shfl_up(w, o);
                if (lane >= o) w += t;
            }
            wsum[lane] = w;
        }
        __syncthreads();
        int wave_off = (wave == 0) ? 0 : wsum[wave - 1];
        int incl = x + wave_off + carry_s;
        if (i < n) rowptr[i] = incl - v;
        __syncthreads();
        if (tid == 0) carry_s += wsum[15];
        __syncthreads();
    }
    if (tid == 0) rowptr[n] = carry_s;
}

__global__ __launch_bounds__(256) void scatter_kernel(
    const int* __restrict__ dst, int* __restrict__ cursor,
    int* __restrict__ esorted, int E)
{
    int e = blockIdx.x * 256 + threadIdx.x;
    if (e < E) {
        int p = atomicAdd(&cursor[dst[e]], 1);
        esorted[p] = e;
    }
}

// ---------------- fused per-node message + aggregate ----------------
__global__ __launch_bounds__(256) void node_agg_kernel(
    const float* __restrict__ P,      // [N,512]
    const int* __restrict__ src,
    const float* __restrict__ attr,   // [E,4]
    const float* __restrict__ W3,     // [4,256]
    const float* __restrict__ be, const float* __restrict__ g1, const float* __restrict__ b1,
    const int* __restrict__ rowptr, const int* __restrict__ esorted,
    float* __restrict__ agg, int N)
{
    const int wave = threadIdx.x >> 6;
    const int lane = threadIdx.x & 63;
    const int n = blockIdx.x * 4 + wave;
    if (n >= N) return;
    const int c0 = lane * 4;

    float4 p1 = *(const float4*)(P + (size_t)n * 512 + c0);
    const float* p1p = (const float*)&p1;

    float w30[4], w31[4], w32[4], w33[4], bev[4], g1v[4], b1v[4];
    #pragma unroll
    for (int i = 0; i < 4; ++i) {
        const int c = c0 + i;
        w30[i] = W3[c]; w31[i] = W3[256 + c]; w32[i] = W3[512 + c]; w33[i] = W3[768 + c];
        bev[i] = be[c]; g1v[i] = g1[c]; b1v[i] = b1[c];
    }

    float acc[4] = {0.f, 0.f, 0.f, 0.f};
    const int beg = rowptr[n];
    const int end = rowptr[n + 1];

    for (int i = beg; i < end; ++i) {
        const int e = esorted[i];
        const int s = src[e];
        float4 ps = *(const float4*)(P + (size_t)s * 512 + 256 + c0);
        const float* psp = (const float*)&ps;
        float4 av = *(const float4*)(attr + (size_t)e * 4);

        float h[4];
        #pragma unroll
        for (int j = 0; j < 4; ++j) {
            float w = av.x * w30[j] + av.y * w31[j] + av.z * w32[j] + av.w * w33[j];
            h[j] = p1p[j] + psp[j] + w + bev[j];
        }

        float sum = wave_sum(h[0] + h[1] + h[2] + h[3]);
        const float mean = sum * (1.0f / 256.0f);
        float vs = 0.f;
        #pragma unroll
        for (int j = 0; j < 4; ++j) { float t = h[j] - mean; vs += t * t; }
        vs = wave_sum(vs);
        const float rstd = rsqrtf(vs * (1.0f / 256.0f) + 1e-5f);

        #pragma unroll
        for (int j = 0; j < 4; ++j) {
            float y = (h[j] - mean) * rstd * g1v[j] + b1v[j];
            acc[j] += y / (1.0f + __expf(-y));
        }
    }

    *(float4*)(agg + (size_t)n * 256 + c0) = make_float4(acc[0], acc[1], acc[2], acc[3]);
}

// In-place LayerNorm + SiLU over rows of u [N,256]; one wave per row.
__global__ __launch_bounds__(256) void ln_silu_kernel(
    float* __restrict__ u, const float* __restrict__ g, const float* __restrict__ b, int N)
{
    const int wave = threadIdx.x >> 6;
    const int lane = threadIdx.x & 63;
    const int r = blockIdx.x * 4 + wave;
    if (r >= N) return;

    float4 hv = *(const float4*)(u + (size_t)r * 256 + lane * 4);
    float h[4] = {hv.x, hv.y, hv.z, hv.w};

    float sum = wave_sum(h[0] + h[1] + h[2] + h[3]);
    const float mean = sum * (1.0f / 256.0f);
    float vs = 0.f;
    #pragma unroll
    for (int i = 0; i < 4; ++i) { float t = h[i] - mean; vs += t * t; }
    vs = wave_sum(vs);
    const float rstd = rsqrtf(vs * (1.0f / 256.0f) + 1e-5f);

    #pragma unroll
    for (int i = 0; i < 4; ++i) {
        const int c = lane * 4 + i;
        float y = (h[i] - mean) * rstd * g[c] + b[c];
        h[i] = y / (1.0f + __expf(-y));
    }
    *(float4*)(u + (size_t)r * 256 + lane * 4) = make_float4(h[0], h[1], h[2], h[3]);
}

extern "C" void kernel_launch(void* const* d_in, const int* in_sizes, int n_in,
                              void* d_out, int out_size, void* d_ws, size_t ws_size,
                              hipStream_t stream) {
    const float* mesh   = (const float*)d_in[0];
    const int*   eidx   = (const int*)  d_in[1];
    const float* eattr  = (const float*)d_in[2];
    const float* We_w   = (const float*)d_in[3];
    const float* We_b   = (const float*)d_in[4];
    const float* ln1_g  = (const float*)d_in[5];
    const float* ln1_b  = (const float*)d_in[6];
    const float* Wn1_w  = (const float*)d_in[7];
    const float* Wn1_b  = (const float*)d_in[8];
    const float* ln2_g  = (const float*)d_in[9];
    const float* ln2_b  = (const float*)d_in[10];
    const float* Wn2_w  = (const float*)d_in[11];
    const float* Wn2_b  = (const float*)d_in[12];

    const int N = NNODES, E = NEDGES;

    float* x   = (float*)d_out;                 // [N,256]
    float* P   = (float*)d_ws;                  // [N,512]
    float* u   = P;                             // [N,256] aliases P
    float* agg = P + (size_t)N * 512;           // [N,256]
    int*   deg     = (int*)(agg + (size_t)N * 256);
    int*   rowptr  = deg + N;
    int*   cursor  = rowptr + (N + 1);
    int*   esorted = cursor + N;                // E
    uintptr_t wp = (uintptr_t)(esorted + E);
    wp = (wp + 63) & ~(uintptr_t)63;
    unsigned short* BTe  = (unsigned short*)wp;            // [6][512][256]
    unsigned short* BTn1 = BTe  + (size_t)6 * 512 * 256;   // [6][256][512]
    unsigned short* BTn2 = BTn1 + (size_t)6 * 256 * 512;   // [6][256][256]

    const int* src = eidx;
    const int* dst = eidx + E;

    hipMemcpyAsync(x, mesh, (size_t)N * 256 * sizeof(float),
                   hipMemcpyDeviceToDevice, stream);

    // ---- weight prep: bf16 [N][K] transposes ----
    // We: 12 batches (6 layers x 2 halves of 256 rows) -> BTe[l][c(512)][k(256)]
    wprep_kernel<<<dim3(8, 8, 12), 256, 0, stream>>>(
        We_w, BTe, 256, 256, (size_t)516 * 256, (size_t)256 * 256, 2);
    // Wn1 [512,256] -> BTn1[l][256][512]
    wprep_kernel<<<dim3(8, 16, 6), 256, 0, stream>>>(
        Wn1_w, BTn1, 512, 256, (size_t)512 * 256, 0, 1);
    // Wn2 [256,256] -> BTn2[l][256][256]
    wprep_kernel<<<dim3(8, 8, 6), 256, 0, stream>>>(
        Wn2_w, BTn2, 256, 256, (size_t)256 * 256, 0, 1);

    // ---- CSR build ----
    hipMemsetAsync(deg, 0, (size_t)N * sizeof(int), stream);
    count_kernel<<<(E + 255) / 256, 256, 0, stream>>>(dst, deg, E);
    scan_kernel<<<1, 1024, 0, stream>>>(deg, rowptr, N);
    hipMemcpyAsync(cursor, rowptr, (size_t)N * sizeof(int),
                   hipMemcpyDeviceToDevice, stream);
    scatter_kernel<<<(E + 255) / 256, 256, 0, stream>>>(dst, cursor, esorted, E);

    const int mblocks = (N + 127) / 128;   // 321
    const int node_blocks = (N + 3) / 4;

    for (int l = 0; l < NLAYERS; ++l) {
        const float* W3  = We_w + (size_t)l * 516 * 256 + (size_t)512 * 256;
        const float* be  = We_b  + (size_t)l * 256;
        const float* g1  = ln1_g + (size_t)l * 256;
        const float* b1  = ln1_b + (size_t)l * 256;
        const float* bn1 = Wn1_b + (size_t)l * 256;
        const float* g2  = ln2_g + (size_t)l * 256;
        const float* b2  = ln2_b + (size_t)l * 256;
        const float* bn2 = Wn2_b + (size_t)l * 256;
        const unsigned short* bte  = BTe  + (size_t)l * 512 * 256;
        const unsigned short* btn1 = BTn1 + (size_t)l * 256 * 512;
        const unsigned short* btn2 = BTn2 + (size_t)l * 256 * 256;

        // P = x @ [W1|W2]  -> [N,512]
        gemm_mfma<<<dim3(mblocks, 4), 256, 0, stream>>>(
            x, nullptr, bte, nullptr, nullptr, P, N, 256, 512);
        // agg[n] = sum over incident edges of silu(LN(h))
        node_agg_kernel<<<node_blocks, 256, 0, stream>>>(
            P, src, eattr, W3, be, g1, b1, rowptr, esorted, agg, N);
        // u = [x | agg] @ Wn1 + bn1   (u aliases P)
        gemm_mfma<<<dim3(mblocks, 2), 256, 0, stream>>>(
            x, agg, btn1, bn1, nullptr, u, N, 512, 256);
        // u = silu(LN(u))
        ln_silu_kernel<<<node_blocks, 256, 0, stream>>>(u, g2, b2, N);
        // x = x + u @ Wn2 + bn2
        gemm_mfma<<<dim3(mblocks, 2), 256, 0, stream>>>(
            u, nullptr, btn2, bn2, x, x, N, 256, 256);
    }
}